// Round 7
// baseline (41.467 us; speedup 1.0000x reference)
//
#include <hip/hip_runtime.h>

#define BB 32
#define RR 56
#define CC 56
#define CHG 64                      // channel float4-groups (256/4)
#define TP 2                        // output pixels per thread (along C)
#define CSEG (CC / TP)              // 28
#define SEGS (BB * RR * CSEG)       // 50176 wave-segments
#define NBLK (SEGS / 4)             // 12544 blocks (4 waves each), % 8 == 0

typedef float nf4 __attribute__((ext_vector_type(4)));

// One wave per 2-pixel row segment; lane = channel group. Lighter waves, 2x
// wave count vs TP=4 — probing the TLP/latency bound. NT stores kept (free).
__global__ __launch_bounds__(256) void dwconv3x3_res6(
    const float4* __restrict__ xv,
    const float4* __restrict__ kv,
    float4* __restrict__ ov)
{
    const int bid = (int)blockIdx.x;
    const int swz = (bid & 7) * (NBLK / 8) + (bid >> 3);  // XCD-chunked swizzle
    const int tid = swz * 256 + (int)threadIdx.x;
    const int seg = tid >> 6;
    const int lane = tid & 63;

    const int b   = seg / (RR * CSEG);
    const int rem = seg - b * (RR * CSEG);
    const int r   = rem / CSEG;
    const int cs  = rem - r * CSEG;
    const int c0  = cs * TP;

    // kernel taps: 3x3 x float4; center (t=4) masked in reference
    float4 kt[9];
    #pragma unroll
    for (int t = 0; t < 9; ++t)
        if (t != 4) kt[t] = kv[t * CHG + lane];

    float4 row[3][TP + 2];
    const int pixbase = (b * RR + r) * CC + c0;

    const bool interior = (r > 0) & (r < RR - 1) & (cs > 0) & (cs < CSEG - 1);
    if (interior) {
        // wave-uniform branch (r, cs identical across lanes)
        #pragma unroll
        for (int dr = 0; dr < 3; ++dr) {
            const int rowbase = (pixbase + (dr - 1) * CC - 1) * CHG + lane;
            #pragma unroll
            for (int j = 0; j < TP + 2; ++j)
                row[dr][j] = xv[rowbase + j * CHG];
        }
    } else {
        #pragma unroll
        for (int dr = 0; dr < 3; ++dr) {
            const int rr2 = r + dr - 1;
            #pragma unroll
            for (int j = 0; j < TP + 2; ++j) {
                const int cc2 = c0 + j - 1;
                float4 v = make_float4(0.f, 0.f, 0.f, 0.f);
                if (rr2 >= 0 && rr2 < RR && cc2 >= 0 && cc2 < CC)
                    v = xv[((b * RR + rr2) * CC + cc2) * CHG + lane];
                row[dr][j] = v;
            }
        }
    }

    #pragma unroll
    for (int p = 0; p < TP; ++p) {
        float4 acc = row[1][p + 1];   // residual (center tap zeroed)
        #pragma unroll
        for (int dr = 0; dr < 3; ++dr) {
            #pragma unroll
            for (int dc = 0; dc < 3; ++dc) {
                if (dr == 1 && dc == 1) continue;
                const float4 kk = kt[dr * 3 + dc];
                const float4 xx = row[dr][p + dc];
                acc.x += kk.x * xx.x;
                acc.y += kk.y * xx.y;
                acc.z += kk.z * xx.z;
                acc.w += kk.w * xx.w;
            }
        }
        nf4 accv = { acc.x, acc.y, acc.z, acc.w };
        __builtin_nontemporal_store(accv, (nf4*)&ov[(pixbase + p) * CHG + lane]);
    }
}

extern "C" void kernel_launch(void* const* d_in, const int* in_sizes, int n_in,
                              void* d_out, int out_size, void* d_ws, size_t ws_size,
                              hipStream_t stream)
{
    const float4* xv = (const float4*)d_in[0];
    const float4* kv = (const float4*)d_in[1];
    float4* ov       = (float4*)d_out;

    dwconv3x3_res6<<<NBLK, 256, 0, stream>>>(xv, kv, ov);
}